// Round 4
// baseline (372.729 us; speedup 1.0000x reference)
//
#include <hip/hip_runtime.h>
#include <math.h>

#define CH   256
#define C8K  32
#define NPOS 4096
#define BQ   4

typedef __attribute__((ext_vector_type(8))) short bf16x8;   // 8 bf16 = 4 VGPR
typedef __attribute__((ext_vector_type(4))) float f32x4;

__device__ __forceinline__ unsigned short f2bf(float f) {   // RNE float->bf16
    unsigned int u = __float_as_uint(f);
    u = (u + 0x7FFFu + ((u >> 16) & 1u)) >> 16;
    return (unsigned short)u;
}
__device__ __forceinline__ float bf2f(unsigned int h) {
    return __uint_as_float(h << 16);
}

// ---------------------------------------------------------------------------
// Projection. grid (64 n-tiles, 2 row-halves, 4 b), block 256, 2 blocks/CU.
// Outputs: Qhi/Qlo/Khi/Klo [b][n][32] bf16 (TRANSPOSED, MFMA-fragment-ready),
//          Vw [b][c][n] bf16.
// x staged transposed in LDS [64 n][132 ch] fp32, XOR swizzle on the ch-quad
// index -> conflict-free b128 reads.
// ---------------------------------------------------------------------------
__global__ __launch_bounds__(256, 2) void proj_kernel(
    const float* __restrict__ x1,
    const float* __restrict__ Wq, const float* __restrict__ bq,
    const float* __restrict__ Wk, const float* __restrict__ bk,
    const float* __restrict__ Wv, const float* __restrict__ bv,
    unsigned short* __restrict__ Qhi, unsigned short* __restrict__ Qlo,
    unsigned short* __restrict__ Khi, unsigned short* __restrict__ Klo,
    unsigned short* __restrict__ Vw)
{
    __shared__ __align__(16) float xT[64 * 132];
    const int t  = threadIdx.x;
    const int rh = blockIdx.y;            // row half: 0 -> rows 0..159, 1 -> 160..319
    const int b  = blockIdx.z;
    const int n0 = blockIdx.x * 64;
    const int n  = t & 63;
    const int og = __builtin_amdgcn_readfirstlane(t >> 6);   // wave id 0..3 (SGPR)

    float a[5][8];
    #pragma unroll
    for (int rc = 0; rc < 5; ++rc)
        #pragma unroll
        for (int j = 0; j < 8; ++j) a[rc][j] = 0.f;

    for (int h = 0; h < 2; ++h) {
        // ---- stage x1[b][h*128 + c][n-tile] transposed+swizzled ----
        {
            const int nq = t & 15, c0 = t >> 4;
            #pragma unroll
            for (int i = 0; i < 8; ++i) {
                const int c = c0 + (i << 4);            // ch within half, 0..127
                const float4 v = *reinterpret_cast<const float4*>(
                    x1 + ((size_t)(b * CH + h * 128 + c) * NPOS) + n0 + nq * 4);
                const int cq = c >> 2, cb = c & 3;
                #pragma unroll
                for (int r = 0; r < 4; ++r) {
                    const int row = nq * 4 + r;
                    const int csw = 4 * (cq ^ ((row & 7) << 2)) + cb;
                    const float* pv4 = &v.x;
                    xT[row * 132 + csw] = pv4[r];
                }
            }
        }
        __syncthreads();

        const float4* xrow4 = reinterpret_cast<const float4*>(xT + n * 132);
        const int nsw = (n & 7) << 2;

        #pragma unroll
        for (int rc = 0; rc < 5; ++rc) {
            const int R0 = rh * 160 + og * 40 + rc * 8;  // 8-row chunk, 8-aligned
            const float* wbase;
            int r0;
            if (R0 < 32)      { wbase = Wq; r0 = R0;      }
            else if (R0 < 64) { wbase = Wk; r0 = R0 - 32; }
            else              { wbase = Wv; r0 = R0 - 64; }
            const float4* w4 = reinterpret_cast<const float4*>(wbase + r0 * CH + h * 128);

            #pragma unroll 4
            for (int cq = 0; cq < 32; ++cq) {
                const float4 xv = xrow4[cq ^ nsw];
                #pragma unroll
                for (int j = 0; j < 8; ++j) {
                    const float4 wv = w4[j * 64 + cq];   // wave-uniform -> scalar loads
                    a[rc][j] += wv.x * xv.x + wv.y * xv.y + wv.z * xv.z + wv.w * xv.w;
                }
            }
        }
        __syncthreads();   // before h=1 overwrites xT
    }

    // ---- outputs ----
    #pragma unroll
    for (int rc = 0; rc < 5; ++rc) {
        const int R0 = rh * 160 + og * 40 + rc * 8;
        const float* bias_p; int r0, kind;
        if (R0 < 32)      { bias_p = bq; r0 = R0;      kind = 0; }
        else if (R0 < 64) { bias_p = bk; r0 = R0 - 32; kind = 1; }
        else              { bias_p = bv; r0 = R0 - 64; kind = 2; }

        float val[8];
        #pragma unroll
        for (int j = 0; j < 8; ++j) val[j] = a[rc][j] + bias_p[r0 + j];

        if (kind < 2) {
            unsigned short hi[8], lo[8];
            #pragma unroll
            for (int j = 0; j < 8; ++j) {
                hi[j] = f2bf(val[j]);
                lo[j] = f2bf(val[j] - bf2f((unsigned int)hi[j]));
            }
            unsigned short* dhi = (kind == 0) ? Qhi : Khi;
            unsigned short* dlo = (kind == 0) ? Qlo : Klo;
            const size_t off = ((size_t)b * NPOS + n0 + n) * C8K + r0;  // 16B aligned
            uint4 ph, pl;
            ph.x = (unsigned)hi[0] | ((unsigned)hi[1] << 16);
            ph.y = (unsigned)hi[2] | ((unsigned)hi[3] << 16);
            ph.z = (unsigned)hi[4] | ((unsigned)hi[5] << 16);
            ph.w = (unsigned)hi[6] | ((unsigned)hi[7] << 16);
            pl.x = (unsigned)lo[0] | ((unsigned)lo[1] << 16);
            pl.y = (unsigned)lo[2] | ((unsigned)lo[3] << 16);
            pl.z = (unsigned)lo[4] | ((unsigned)lo[5] << 16);
            pl.w = (unsigned)lo[6] | ((unsigned)lo[7] << 16);
            *reinterpret_cast<uint4*>(dhi + off) = ph;
            *reinterpret_cast<uint4*>(dlo + off) = pl;
        } else {
            #pragma unroll
            for (int j = 0; j < 8; ++j)
                Vw[((size_t)b * CH + r0 + j) * NPOS + n0 + n] = f2bf(val[j]);
        }
    }
}

// ---------------------------------------------------------------------------
// MFMA flash attention. grid 256 = (4 b) x (64 m-tiles of 64), block 512
// (8 waves = 2/SIMD). Wave w: m-half mh=w>>2 (32 m's), n-slot ns=w&3 (16 n's).
// No max-subtraction (|S| <~ 35 << 88: fp32-exp safe; bf16 P max ~2e15: safe).
// Per key-tile: S' = mfma(A=K,B=Q) x3 (hi/lo split), exp fp32, P->bf16 b64 to
// LDS; V bf16 staged (loads issued early, T14); PV = mfma(A=P,B=V layout).
// Zero LDS in S phase (Q frags in regs all 64 tiles; K frags from global,
// L2-resident, prefetched during PV). 2 barriers/tile. Static LDS 47360 B.
// LDS row stride 72 ushorts = 9 x 16B slots (odd) -> conflict-free b128.
// ---------------------------------------------------------------------------
__global__ __launch_bounds__(512, 2) void attn_kernel(
    const unsigned short* __restrict__ Qhi, const unsigned short* __restrict__ Qlo,
    const unsigned short* __restrict__ Khi, const unsigned short* __restrict__ Klo,
    const unsigned short* __restrict__ Vw,  const float* __restrict__ x1,
    const float* __restrict__ gamma, float* __restrict__ out)
{
    __shared__ __align__(16) unsigned char smem[47360];
    float*          smWave = (float*)smem;                        // [8][32]
    float*          smInv  = (float*)(smem + 1024);               // [64]
    unsigned short* Vt     = (unsigned short*)(smem + 1280);      // [256][72] bf16
    unsigned short* Pt     = (unsigned short*)(smem + 1280 + 36864); // [64][72] bf16
    unsigned short* Ot     = Vt;                                  // epilogue alias

    const int t      = threadIdx.x;
    const int l      = t & 63;
    const int w      = t >> 6;        // wave 0..7
    const int ns     = w & 3;         // n-slot (16 keys)
    const int mh     = w >> 2;        // m-half (32 queries)
    const int lane15 = l & 15;
    const int g      = l >> 4;        // 0..3

    const int b  = blockIdx.x >> 6;
    const int m0 = (blockIdx.x & 63) << 6;

    const size_t qkBase = (size_t)b * NPOS * C8K;

    // ---- Q fragments in registers, reused across all 64 key-tiles ----
    bf16x8 qh[2], ql[2];
    #pragma unroll
    for (int j = 0; j < 2; ++j) {
        const size_t off = qkBase + (size_t)(m0 + (mh * 2 + j) * 16 + lane15) * C8K + g * 8;
        qh[j] = *reinterpret_cast<const bf16x8*>(Qhi + off);
        ql[j] = *reinterpret_cast<const bf16x8*>(Qlo + off);
    }
    // ---- K fragment base (n = n0 + ns*16 + lane15), prologue loads tile 0 ----
    const size_t kOffBase = qkBase + (size_t)(ns * 16 + lane15) * C8K + g * 8;
    bf16x8 kh = *reinterpret_cast<const bf16x8*>(Khi + kOffBase);
    bf16x8 kl = *reinterpret_cast<const bf16x8*>(Klo + kOffBase);

    // V staging: thread -> (vcq = t>>3 in 0..63, vng = t&7); 4 rows of 8 bf16
    const int vcq = t >> 3, vng = t & 7;
    const unsigned short* vsrcBase = Vw + (size_t)b * CH * NPOS + vng * 8;

    f32x4 acc[2][4];   // [j][ct]: D[m = mh*32+j*16+g*4+r][c = ns*64+ct*16+lane15]
    #pragma unroll
    for (int j = 0; j < 2; ++j)
        #pragma unroll
        for (int ct = 0; ct < 4; ++ct)
            acc[j][ct] = (f32x4){0.f, 0.f, 0.f, 0.f};
    float psum[2] = {0.f, 0.f};

    for (int nt = 0; nt < 64; ++nt) {
        const int n0 = nt << 6;
        __syncthreads();   // A: previous PV finished reading Pt/Vt

        // issue V loads for this tile (latency hides under S phase)
        uint4 vld[4];
        #pragma unroll
        for (int i = 0; i < 4; ++i)
            vld[i] = *reinterpret_cast<const uint4*>(
                vsrcBase + (size_t)(vcq + 64 * i) * NPOS + n0);

        // ---- S' tiles: D[n_local][m] = sum_ch K[ch][n] Q[ch][m], hi/lo x3 ----
        // C/D map: lane l, reg r -> row (n_local) = g*4+r, col (m_local) = lane15
        float pe[2][4];
        #pragma unroll
        for (int j = 0; j < 2; ++j) {
            f32x4 s = (f32x4){0.f, 0.f, 0.f, 0.f};
            s = __builtin_amdgcn_mfma_f32_16x16x32_bf16(kh, qh[j], s, 0, 0, 0);
            s = __builtin_amdgcn_mfma_f32_16x16x32_bf16(kh, ql[j], s, 0, 0, 0);
            s = __builtin_amdgcn_mfma_f32_16x16x32_bf16(kl, qh[j], s, 0, 0, 0);
            #pragma unroll
            for (int r = 0; r < 4; ++r) {
                const float e = __expf(s[r]);
                pe[j][r] = e;
                psum[j] += e;
            }
        }
        // ---- pack P -> bf16: Pt[m = (mh*2+j)*16+lane15][n = ns*16+g*4+{0..3}] ----
        #pragma unroll
        for (int j = 0; j < 2; ++j) {
            uint2 pk;
            pk.x = (unsigned)f2bf(pe[j][0]) | ((unsigned)f2bf(pe[j][1]) << 16);
            pk.y = (unsigned)f2bf(pe[j][2]) | ((unsigned)f2bf(pe[j][3]) << 16);
            *reinterpret_cast<uint2*>(
                Pt + ((mh * 2 + j) * 16 + lane15) * 72 + ns * 16 + g * 4) = pk;
        }
        // ---- write V tile (loads landed during S phase) ----
        #pragma unroll
        for (int i = 0; i < 4; ++i)
            *reinterpret_cast<uint4*>(Vt + (vcq + 64 * i) * 72 + vng * 8) = vld[i];

        // ---- prefetch K fragments for next tile (consumed next iteration) ----
        {
            const int nn = (nt < 63) ? (n0 + 64) : n0;
            kh = *reinterpret_cast<const bf16x8*>(Khi + kOffBase + (size_t)nn * C8K);
            kl = *reinterpret_cast<const bf16x8*>(Klo + kOffBase + (size_t)nn * C8K);
        }
        __syncthreads();   // B: Pt + Vt ready

        // ---- PV: acc[m][c] += sum_n P[m][n] V[c][n] ----
        #pragma unroll
        for (int ks = 0; ks < 2; ++ks) {
            bf16x8 pa[2], vb[4];
            #pragma unroll
            for (int j = 0; j < 2; ++j)
                pa[j] = *reinterpret_cast<const bf16x8*>(
                    Pt + (mh * 32 + j * 16 + lane15) * 72 + ks * 32 + g * 8);
            #pragma unroll
            for (int ct = 0; ct < 4; ++ct)
                vb[ct] = *reinterpret_cast<const bf16x8*>(
                    Vt + (ns * 64 + ct * 16 + lane15) * 72 + ks * 32 + g * 8);
            #pragma unroll
            for (int j = 0; j < 2; ++j)
                #pragma unroll
                for (int ct = 0; ct < 4; ++ct)
                    acc[j][ct] = __builtin_amdgcn_mfma_f32_16x16x32_bf16(
                        pa[j], vb[ct], acc[j][ct], 0, 0, 0);
        }
    }

    // ---- denominator: reduce psum over g (shfl), combine n-slots via LDS ----
    #pragma unroll
    for (int j = 0; j < 2; ++j) {
        float v = psum[j];
        v += __shfl_xor(v, 16, 64);
        v += __shfl_xor(v, 32, 64);
        psum[j] = v;
    }
    if (l < 16) {
        #pragma unroll
        for (int j = 0; j < 2; ++j)
            smWave[w * 32 + j * 16 + lane15] = psum[j];
    }
    __syncthreads();   // all waves done with loop + smWave written
    if (t < 64) {
        const int mh2 = t >> 5, ml = t & 31;
        const float d = smWave[(mh2 * 4 + 0) * 32 + ml] + smWave[(mh2 * 4 + 1) * 32 + ml]
                      + smWave[(mh2 * 4 + 2) * 32 + ml] + smWave[(mh2 * 4 + 3) * 32 + ml];
        smInv[t] = 1.f / d;
    }
    __syncthreads();

    // ---- normalize, stash transposed (Ot[c][m], bf16, aliases dead Vt) ----
    #pragma unroll
    for (int j = 0; j < 2; ++j) {
        const float4 inv4 = *reinterpret_cast<const float4*>(smInv + mh * 32 + j * 16 + g * 4);
        #pragma unroll
        for (int ct = 0; ct < 4; ++ct) {
            const int c = ns * 64 + ct * 16 + lane15;
            const f32x4 a = acc[j][ct];
            uint2 pk;
            pk.x = (unsigned)f2bf(a[0] * inv4.x) | ((unsigned)f2bf(a[1] * inv4.y) << 16);
            pk.y = (unsigned)f2bf(a[2] * inv4.z) | ((unsigned)f2bf(a[3] * inv4.w) << 16);
            *reinterpret_cast<uint2*>(Ot + c * 72 + mh * 32 + j * 16 + g * 4) = pk;
        }
    }
    __syncthreads();

    // ---- fused out = gamma * att + x1, coalesced ----
    const float gm = gamma[0];
    {
        const int mq = t & 15, c0 = t >> 4;   // c0 0..31
        #pragma unroll 4
        for (int i = 0; i < 8; ++i) {
            const int c = c0 + (i << 5);
            const size_t off = ((size_t)(b * CH + c)) * NPOS + m0 + mq * 4;
            const uint2 pk = *reinterpret_cast<const uint2*>(Ot + c * 72 + mq * 4);
            const float4 xv = *reinterpret_cast<const float4*>(x1 + off);
            float4 ov;
            ov.x = gm * bf2f(pk.x & 0xFFFFu)  + xv.x;
            ov.y = gm * bf2f(pk.x >> 16)      + xv.y;
            ov.z = gm * bf2f(pk.y & 0xFFFFu)  + xv.z;
            ov.w = gm * bf2f(pk.y >> 16)      + xv.w;
            *reinterpret_cast<float4*>(out + off) = ov;
        }
    }
}

// ---------------------------------------------------------------------------
extern "C" void kernel_launch(void* const* d_in, const int* in_sizes, int n_in,
                              void* d_out, int out_size, void* d_ws, size_t ws_size,
                              hipStream_t stream)
{
    const float* x1    = (const float*)d_in[0];
    // d_in[1] = x2 : unused by the reference
    const float* Wq    = (const float*)d_in[2];
    const float* bq    = (const float*)d_in[3];
    const float* Wk    = (const float*)d_in[4];
    const float* bk    = (const float*)d_in[5];
    const float* Wv    = (const float*)d_in[6];
    const float* bv    = (const float*)d_in[7];
    const float* gamma = (const float*)d_in[8];
    float* out = (float*)d_out;

    // workspace (ushort elems): Qhi|Qlo|Khi|Klo each 4*4096*32, then Vw 4*256*4096
    unsigned short* ws  = (unsigned short*)d_ws;
    const size_t QK     = (size_t)BQ * NPOS * C8K;        // 524288
    unsigned short* Qhi = ws;
    unsigned short* Qlo = ws + QK;
    unsigned short* Khi = ws + 2 * QK;
    unsigned short* Klo = ws + 3 * QK;
    unsigned short* Vw  = ws + 4 * QK;                    // 4*256*4096 ushorts

    proj_kernel<<<dim3(64, 2, BQ), 256, 0, stream>>>(
        x1, Wq, bq, Wk, bk, Wv, bv, Qhi, Qlo, Khi, Klo, Vw);

    attn_kernel<<<dim3(256), 512, 0, stream>>>(
        Qhi, Qlo, Khi, Klo, Vw, x1, gamma, out);
}